// Round 3
// baseline (879.209 us; speedup 1.0000x reference)
//
#include <hip/hip_runtime.h>

// MorphogenField: 10 fused diffusion+decay steps, B=8,M=4,H=1024,W=1024 fp32.
// v3b: fully wave-private tile. 64-thread blocks; each lane owns 12 rows x 12
// cols in VGPRs (8 strips x 8 col-groups = 96x96 region -> 64x64 output).
// ALL neighbor exchange is intra-wave __shfl: zero LDS, zero barriers.
// vs v3: outer step loop ROLLED (#pragma unroll 1) -- inner RPL loop stays
// fully unrolled for static T[i] indexing, but body shrinks ~10x (fits L1i,
// fast compile). No algorithmic change.
constexpr int Hv = 1024, Wv = 1024;
constexpr int TILE   = 64;
constexpr int HALO_R = 10;               // rows halo = steps (exact margin)
constexpr int CHALO  = 16;               // cols halo (float4-aligned, margin 6)
constexpr int RPL    = 12;               // rows per lane
constexpr int STEPS  = 10;               // from setup_inputs()

// o = c*(1-4d-k) + d*(l+r+u+dn): 3 adds + 1 mul + 1 fma per element.
__device__ __forceinline__ float4 upd4(const float4 c, const float4 u, const float4 d,
                                       const float lf, const float rt,
                                       const float dif, const float cdec)
{
    float4 o;
    o.x = fmaf(cdec, c.x, dif * ((lf  + c.y) + (u.x + d.x)));
    o.y = fmaf(cdec, c.y, dif * ((c.x + c.z) + (u.y + d.y)));
    o.z = fmaf(cdec, c.z, dif * ((c.y + c.w) + (u.z + d.z)));
    o.w = fmaf(cdec, c.w, dif * ((c.z + rt ) + (u.w + d.w)));
    return o;
}

// staging load with edge-broadcast semantics (same as v1/v2, harness-verified)
__device__ __forceinline__ float4 ldrow4(const float* __restrict__ rowp, int gc)
{
    if (gc < 0)        { float e = rowp[0];      return make_float4(e, e, e, e); }
    if (gc > Wv - 4)   { float e = rowp[Wv - 1]; return make_float4(e, e, e, e); }
    return *(const float4*)(rowp + gc);
}

__device__ __forceinline__ float4 shflup4(const float4 v, int d)
{
    return make_float4(__shfl_up(v.x, d), __shfl_up(v.y, d),
                       __shfl_up(v.z, d), __shfl_up(v.w, d));
}
__device__ __forceinline__ float4 shfldn4(const float4 v, int d)
{
    return make_float4(__shfl_down(v.x, d), __shfl_down(v.y, d),
                       __shfl_down(v.z, d), __shfl_down(v.w, d));
}

__global__ __launch_bounds__(64, 2)
void morpho_wave(const float* __restrict__ src, float* __restrict__ dst,
                 const float* __restrict__ dr,  const float* __restrict__ kr)
{
    const int b  = blockIdx.x;
    const int bx = b & 15, by = (b >> 4) & 15, plane = b >> 8;
    const float dif  = dr[plane & 3];
    const float dec  = kr[plane & 3];
    const float cdec = 1.0f - 4.0f * dif - dec;
    const int r0 = by * TILE, c0 = bx * TILE;
    const int tid = threadIdx.x;          // 0..63, one wave
    const int h = tid & 7;                // col group: local cols 12h..12h+11
    const int s = tid >> 3;               // strip: local rows 12s..12s+11

    const float* sp = src + ((size_t)plane << 20);

    // ---- stage own 12x12 sub-tile into registers (globally clamped) ----
    float4 T[RPL][3];                     // [row][f4-group], 144 VGPRs of state
    {
        const int rb = r0 - HALO_R + RPL * s;
        const int cb = c0 - CHALO + 12 * h;
        #pragma unroll
        for (int i = 0; i < RPL; ++i) {
            const float* rp = sp + ((size_t)min(max(rb + i, 0), Hv - 1) << 10);
            T[i][0] = ldrow4(rp, cb);
            T[i][1] = ldrow4(rp, cb + 4);
            T[i][2] = ldrow4(rp, cb + 8);
        }
    }

    // domain-edge clamps (lane-constant). local row 10 == global row 0 is
    // strip 0 slot 10; local row 73 == global row 1023 is strip 6 slot 1.
    const bool lclamp = (bx == 0)  && (h == 1);
    const bool rclamp = (bx == 15) && (h == 6);
    const bool tclamp = (by == 0)  && (s == 0);
    const bool bclamp = (by == 15) && (s == 6);

    // junk-margin induction (as v2): shfl at wave/strip edges feeds only the
    // junk frame (rows 0..9 / 86..95, cols 0..9 / 86..95 after 10 steps);
    // output region rows 10..73 x cols 16..79 is exact. All junk stays finite
    // (out-of-range shfl returns own value; staging is globally clamped).
    #pragma unroll 1
    for (int t = 0; t < STEPS; ++t) {
        // old boundary rows via intra-wave shuffle (convergent, up front):
        // row above strip  = neighbor's row 11;  row below = neighbor's row 0.
        float4 U0 = shflup4(T[RPL-1][0], 8), U1 = shflup4(T[RPL-1][1], 8), U2 = shflup4(T[RPL-1][2], 8);
        float4 D0 = shfldn4(T[0][0], 8),     D1 = shfldn4(T[0][1], 8),     D2 = shfldn4(T[0][2], 8);

        float4 P0 = U0, P1 = U1, P2 = U2;  // old row above current slot
        #pragma unroll
        for (int i = 0; i < RPL; ++i) {
            const float4 a  = T[i][0], b4 = T[i][1], c4 = T[i][2];   // old center
            float4 d0, d1, d2;
            if (i < RPL - 1) { d0 = T[i+1][0]; d1 = T[i+1][1]; d2 = T[i+1][2]; }
            else             { d0 = D0;        d1 = D1;        d2 = D2;        }
            float4 u0 = P0, u1 = P1, u2 = P2;
            if (i == 10) {   // global row 0: up-neighbor := self (only by==0,s==0)
                u0 = tclamp ? a : u0; u1 = tclamp ? b4 : u1; u2 = tclamp ? c4 : u2;
            }
            if (i == 1) {    // global row 1023: down-neighbor := self
                d0 = bclamp ? a : d0; d1 = bclamp ? b4 : d1; d2 = bclamp ? c4 : d2;
            }
            // horizontal neighbors (old values; junk-safe at lane edges)
            float lv = __shfl_up(c4.w, 1);       // left of col 12h
            float rv = __shfl_down(a.x, 1);      // right of col 12h+11
            float lA = lclamp ? b4.x : a.w;      // left of global col 0
            float rA = rclamp ? b4.w : c4.x;     // right of global col 1023
            float4 n0 = upd4(a,  u0, d0, lv,   b4.x, dif, cdec);
            float4 n1 = upd4(b4, u1, d1, lA,   rA,   dif, cdec);
            float4 n2 = upd4(c4, u2, d2, b4.w, rv,   dif, cdec);
            P0 = a; P1 = b4; P2 = c4;            // old center becomes next "above"
            T[i][0] = n0; T[i][1] = n1; T[i][2] = n2;
        }
    }

    // ---- store center 64x64 (local rows 10..73, cols 16..79) ----
    float* dp = dst + ((size_t)plane << 20);
    const int cbase = 12 * h - CHALO;
    #pragma unroll
    for (int i = 0; i < RPL; ++i) {
        const int lr = RPL * s + i;
        if (lr >= HALO_R && lr < HALO_R + TILE) {
            float* rp_ = dp + ((size_t)(r0 + lr - HALO_R) << 10) + c0;
            if (cbase     >= 0 && cbase     <= TILE - 4) *(float4*)(rp_ + cbase)     = T[i][0];
            if (cbase + 4 >= 0 && cbase + 4 <= TILE - 4) *(float4*)(rp_ + cbase + 4) = T[i][1];
            if (cbase + 8 >= 0 && cbase + 8 <= TILE - 4) *(float4*)(rp_ + cbase + 8) = T[i][2];
        }
    }
}

extern "C" void kernel_launch(void* const* d_in, const int* in_sizes, int n_in,
                              void* d_out, int out_size, void* d_ws, size_t ws_size,
                              hipStream_t stream) {
    const float* init = (const float*)d_in[0];
    const float* dr   = (const float*)d_in[1];
    const float* kr   = (const float*)d_in[2];
    float* out = (float*)d_out;
    // 16x16 tiles per plane x 32 planes; one wave per block
    morpho_wave<<<dim3(16 * 16 * 32), dim3(64), 0, stream>>>(init, out, dr, kr);
}

// Round 5
// 350.197 us; speedup vs baseline: 2.5106x; 2.5106x over previous
//
#include <hip/hip_runtime.h>

// MorphogenField: 10 fused diffusion+decay steps, B=8,M=4,H=1024,W=1024 fp32.
// v4r (resubmission of v4 -- R4 failed at container level with no kernel
// diagnostic; code re-audited for deadlock/OOB/race/spill and found clean).
// 256-thread blocks, 32 strips x 3 rows (96x96 region -> 64x64 tile).
// Vertical neighbor exchange via intra-wave __shfl (strip s±1 = lane ±8);
// only the 3 cross-wave strip boundaries go through a 6 KiB parity-double-
// buffered LDS buffer with ONE __syncthreads per step.
// State is NAMED float4 scalars -> the allocator cannot scratch it
// (v3's T[12][3] array spilled: VGPR=128, WRITE_SIZE 131MB->1.74GB).
constexpr int Hv = 1024, Wv = 1024;
constexpr int TILE   = 64;
constexpr int HALO_R = 10;               // rows halo = steps (exact margin)
constexpr int CHALO  = 16;               // cols halo (float4-aligned, margin 6)
constexpr int STEPS  = 10;               // from setup_inputs()

// o = c*(1-4d-k) + d*(l+r+u+dn): 3 adds + 1 mul + 1 fma per element.
__device__ __forceinline__ float4 upd4(const float4 c, const float4 u, const float4 d,
                                       const float lf, const float rt,
                                       const float dif, const float cdec)
{
    float4 o;
    o.x = fmaf(cdec, c.x, dif * ((lf  + c.y) + (u.x + d.x)));
    o.y = fmaf(cdec, c.y, dif * ((c.x + c.z) + (u.y + d.y)));
    o.z = fmaf(cdec, c.z, dif * ((c.y + c.w) + (u.z + d.z)));
    o.w = fmaf(cdec, c.w, dif * ((c.z + rt ) + (u.w + d.w)));
    return o;
}

// staging load with edge-broadcast semantics (harness-verified in v1/v2)
__device__ __forceinline__ float4 ldrow4(const float* __restrict__ rowp, int gc)
{
    if (gc < 0)        { float e = rowp[0];      return make_float4(e, e, e, e); }
    if (gc > Wv - 4)   { float e = rowp[Wv - 1]; return make_float4(e, e, e, e); }
    return *(const float4*)(rowp + gc);
}

__device__ __forceinline__ float4 shflup4(const float4 v, int d)
{ return make_float4(__shfl_up(v.x,d),__shfl_up(v.y,d),__shfl_up(v.z,d),__shfl_up(v.w,d)); }
__device__ __forceinline__ float4 shfldn4(const float4 v, int d)
{ return make_float4(__shfl_down(v.x,d),__shfl_down(v.y,d),__shfl_down(v.z,d),__shfl_down(v.w,d)); }
__device__ __forceinline__ float4 sel4(bool p, const float4 a, const float4 b)
{ float4 o; o.x=p?a.x:b.x; o.y=p?a.y:b.y; o.z=p?a.z:b.z; o.w=p?a.w:b.w; return o; }

// one row update; P* = old center row, U*/X* = old up/down rows (12 cols).
// Shuffles crossing a strip/wave boundary feed only the junk frame (finite).
#define ROWUPD(Pa,Pb,Pc, Ua,Ub,Uc, Xa,Xb,Xc, Oa,Ob,Oc) do {            \
    float lv_ = __shfl_up((Pc).w, 1);   /* left of col 12h   */        \
    float rv_ = __shfl_down((Pa).x, 1); /* right of col 12h+11 */      \
    float lA_ = lclamp ? (Pb).x : (Pa).w;  /* left of global col 0 */  \
    float rA_ = rclamp ? (Pb).w : (Pc).x;  /* right of col 1023 */     \
    Oa = upd4((Pa), (Ua), (Xa), lv_, (Pb).x, dif, cdec);               \
    Ob = upd4((Pb), (Ub), (Xb), lA_, rA_,    dif, cdec);               \
    Oc = upd4((Pc), (Uc), (Xc), (Pb).w, rv_, dif, cdec);               \
} while (0)

__global__ __launch_bounds__(256, 4)
void morpho_shfl(const float* __restrict__ src, float* __restrict__ dst,
                 const float* __restrict__ dr,  const float* __restrict__ kr)
{
    // cross-wave boundary rows only: [parity][wave][24 float4 = 96 cols]
    __shared__ float4 xbot[2][4][24];    // bottom row (3s+2) of strip s&7==7
    __shared__ float4 xtop[2][4][24];    // top row (3s) of strip s&7==0
    // total 2*2*4*24*16 = 6144 B

    const int b  = blockIdx.x;
    const int bx = b & 15, by = (b >> 4) & 15, plane = b >> 8;
    const float dif  = dr[plane & 3];
    const float dec  = kr[plane & 3];
    const float cdec = 1.0f - 4.0f * dif - dec;
    const int r0 = by * TILE, c0 = bx * TILE;
    const int tid = threadIdx.x;
    const int h = tid & 7;                // col group: local cols 12h..12h+11
    const int s = tid >> 3;               // strip 0..31: local rows 3s..3s+2
    const int w = tid >> 6;               // wave 0..3

    const float* sp = src + ((size_t)plane << 20);

    // ---- stage own 3x12 sub-tile into NAMED registers (globally clamped) ----
    float4 T0a,T0b,T0c, T1a,T1b,T1c, T2a,T2b,T2c;
    {
        const int rb = r0 - HALO_R + 3 * s;
        const int cb = c0 - CHALO + 12 * h;
        const float* rp0 = sp + ((size_t)min(max(rb    , 0), Hv - 1) << 10);
        const float* rp1 = sp + ((size_t)min(max(rb + 1, 0), Hv - 1) << 10);
        const float* rp2 = sp + ((size_t)min(max(rb + 2, 0), Hv - 1) << 10);
        T0a = ldrow4(rp0, cb); T0b = ldrow4(rp0, cb + 4); T0c = ldrow4(rp0, cb + 8);
        T1a = ldrow4(rp1, cb); T1b = ldrow4(rp1, cb + 4); T1c = ldrow4(rp1, cb + 8);
        T2a = ldrow4(rp2, cb); T2b = ldrow4(rp2, cb + 4); T2c = ldrow4(rp2, cb + 8);
    }

    // lane-constant predicates
    const bool lclamp = (bx == 0)  && (h == 1);   // global col 0 = B.x of h==1
    const bool rclamp = (bx == 15) && (h == 6);   // global col 1023 = B.w of h==6
    const bool tclamp = (by == 0)  && (s == 3);   // local row 10 == global row 0 (i=1)
    const bool bclamp = (by == 15) && (s == 24);  // local row 73 == global row 1023 (i=1)
    const bool isBot  = ((s & 7) == 7);           // strip below is in next wave
    const bool isTop  = ((s & 7) == 0);           // strip above is in prev wave
    const bool dsel   = isBot && (w < 3);         // take D from LDS
    const bool usel   = isTop && (w > 0);         // take U from LDS
    const int  wp = min(w + 1, 3), wm = max(w - 1, 0);

    // junk-margin induction: contamination enters only at region edges
    // (rows/cols 0 and 95) and moves 1/step; after 10 steps rows 10..85 x
    // cols 10..85 are exact, covering output rows 10..73 x cols 16..79.
    int par = 0;
    #pragma unroll 1
    for (int t = 0; t < STEPS; ++t) {
        // old down-row (3s+3) = next strip's row 0, captured BEFORE any update
        float4 Da = shfldn4(T0a, 8), Db = shfldn4(T0b, 8), Dc = shfldn4(T0c, 8);

        // publish cross-wave boundary rows (old values), masked writes
        if (isBot) { xbot[par][w][3*h+0] = T2a; xbot[par][w][3*h+1] = T2b; xbot[par][w][3*h+2] = T2c; }
        if (isTop) { xtop[par][w][3*h+0] = T0a; xtop[par][w][3*h+1] = T0b; xtop[par][w][3*h+2] = T0c; }
        __syncthreads();

        // cross-wave reads (unconditional, 8-address broadcast: conflict-free)
        {
            float4 qa = xtop[par][wp][3*h+0], qb = xtop[par][wp][3*h+1], qc = xtop[par][wp][3*h+2];
            Da = sel4(dsel, qa, Da); Db = sel4(dsel, qb, Db); Dc = sel4(dsel, qc, Dc);
        }
        // old up-row (3s-1) = prev strip's row 2; intra-wave lanes are in
        // lockstep, so lane-8's T2 is still the OLD value here.
        float4 Ua = shflup4(T2a, 8), Ub = shflup4(T2b, 8), Uc = shflup4(T2c, 8);
        {
            float4 ra = xbot[par][wm][3*h+0], rb4 = xbot[par][wm][3*h+1], rc = xbot[par][wm][3*h+2];
            Ua = sel4(usel, ra, Ua); Ub = sel4(usel, rb4, Ub); Uc = sel4(usel, rc, Uc);
        }

        // row 0: c=T0, u=U, d=T1(old)
        float4 n0a, n0b, n0c;
        ROWUPD(T0a,T0b,T0c, Ua,Ub,Uc, T1a,T1b,T1c, n0a,n0b,n0c);
        // row 1: u = tclamp? self : T0(old); d = bclamp? self : T2(old)
        float4 u1a = sel4(tclamp, T1a, T0a), u1b = sel4(tclamp, T1b, T0b), u1c = sel4(tclamp, T1c, T0c);
        float4 d1a = sel4(bclamp, T1a, T2a), d1b = sel4(bclamp, T1b, T2b), d1c = sel4(bclamp, T1c, T2c);
        float4 n1a, n1b, n1c;
        ROWUPD(T1a,T1b,T1c, u1a,u1b,u1c, d1a,d1b,d1c, n1a,n1b,n1c);
        T0a = n0a; T0b = n0b; T0c = n0c;          // row 0 old dead now
        // row 2: c=T2, u=T1(old), d=D
        float4 n2a, n2b, n2c;
        ROWUPD(T2a,T2b,T2c, T1a,T1b,T1c, Da,Db,Dc, n2a,n2b,n2c);
        T1a = n1a; T1b = n1b; T1c = n1c;
        T2a = n2a; T2b = n2b; T2c = n2c;
        par ^= 1;
    }

    // ---- store center 64x64 (local rows 10..73, cols 16..79) ----
    float* dp = dst + ((size_t)plane << 20);
    const int cbase = 12 * h - CHALO;
#define STORE_ROW(LR, Pa, Pb, Pc) do {                                             \
        const int lr_ = (LR);                                                      \
        if (lr_ >= HALO_R && lr_ < HALO_R + TILE) {                                \
            float* rp_ = dp + ((size_t)(r0 + lr_ - HALO_R) << 10) + c0;            \
            if (cbase     >= 0 && cbase     <= TILE - 4) *(float4*)(rp_ + cbase)     = Pa; \
            if (cbase + 4 >= 0 && cbase + 4 <= TILE - 4) *(float4*)(rp_ + cbase + 4) = Pb; \
            if (cbase + 8 >= 0 && cbase + 8 <= TILE - 4) *(float4*)(rp_ + cbase + 8) = Pc; \
        } } while (0)

    STORE_ROW(3 * s + 0, T0a, T0b, T0c);
    STORE_ROW(3 * s + 1, T1a, T1b, T1c);
    STORE_ROW(3 * s + 2, T2a, T2b, T2c);
#undef STORE_ROW
}

extern "C" void kernel_launch(void* const* d_in, const int* in_sizes, int n_in,
                              void* d_out, int out_size, void* d_ws, size_t ws_size,
                              hipStream_t stream) {
    const float* init = (const float*)d_in[0];
    const float* dr   = (const float*)d_in[1];
    const float* kr   = (const float*)d_in[2];
    float* out = (float*)d_out;
    // 16x16 tiles per plane x 32 planes
    morpho_shfl<<<dim3(16 * 16 * 32), dim3(256), 0, stream>>>(init, out, dr, kr);
}